// Round 2
// baseline (1062.972 us; speedup 1.0000x reference)
//
#include <hip/hip_runtime.h>
#include <hip/hip_bf16.h>
#include <math.h>

typedef __bf16 bf16x8 __attribute__((ext_vector_type(8)));
typedef float f32x4 __attribute__((ext_vector_type(4)));

#define GPTR(x) ((const __attribute__((address_space(1))) void*)(x))
#define LPTR(x) ((__attribute__((address_space(3))) void*)(x))

__device__ __forceinline__ void gload_lds16(const void* g, void* l) {
  __builtin_amdgcn_global_load_lds(GPTR(g), LPTR(l), 16, 0, 0);
}

// ---------------- cast fp32 -> bf16, vectorized ----------------
__global__ __launch_bounds__(256) void cast_f32_bf16(const float* __restrict__ in,
                                                     __hip_bfloat16* __restrict__ out,
                                                     int n4) {
  int i = blockIdx.x * 256 + threadIdx.x;
  if (i >= n4) return;
  float4 v = ((const float4*)in)[i];
  __hip_bfloat16 t[4];
  t[0] = __float2bfloat16(v.x); t[1] = __float2bfloat16(v.y);
  t[2] = __float2bfloat16(v.z); t[3] = __float2bfloat16(v.w);
  ((uint2*)out)[i] = *(uint2*)t;
}

// ---------------- RoPE tables: cos/sin[s][j], j<64 ----------------
__global__ __launch_bounds__(256) void rope_tables(float* __restrict__ cosT,
                                                   float* __restrict__ sinT, int S) {
  int i = blockIdx.x * 256 + threadIdx.x;
  if (i >= S * 64) return;
  int j = i & 63, s = i >> 6;
  float freq = powf(10000.0f, -(float)(2 * j) * (1.0f / 128.0f));
  float a = (float)s * freq;
  cosT[i] = cosf(a);
  sinT[i] = sinf(a);
}

// ---------------- RoPE in-place on q,k halves of qkv (bf16) ----------------
// one thread per (row, h, j) pair; handles q and k.
__global__ __launch_bounds__(256) void rope_apply(__hip_bfloat16* __restrict__ qkv,
                                                  const float* __restrict__ cosT,
                                                  const float* __restrict__ sinT,
                                                  int BS, int S) {
  int i = blockIdx.x * 256 + threadIdx.x;
  if (i >= BS * 1024) return;           // 16 heads * 64 pairs
  int j = i & 63;
  int h = (i >> 6) & 15;
  int row = i >> 10;                    // b*S + s
  int s = row % S;
  float c = cosT[s * 64 + j], sn = sinT[s * 64 + j];
  size_t base = (size_t)row * 6144 + h * 128 + 2 * j;
  {
    __hip_bfloat16* p = qkv + base;     // q
    float x1 = __bfloat162float(p[0]), x2 = __bfloat162float(p[1]);
    p[0] = __float2bfloat16(x1 * c - x2 * sn);
    p[1] = __float2bfloat16(x1 * sn + x2 * c);
  }
  {
    __hip_bfloat16* p = qkv + base + 2048;  // k
    float x1 = __bfloat162float(p[0]), x2 = __bfloat162float(p[1]);
    p[0] = __float2bfloat16(x1 * c - x2 * sn);
    p[1] = __float2bfloat16(x1 * sn + x2 * c);
  }
}

// ---------------- GEMM: C[M][N] = A[M][K] @ B[N][K]^T + bias ----------------
// m97 structure: 128x128 tile, BK=32, 4 waves (64x64 each), global_load_lds w16.
template <int OUT_BF16>
__global__ __launch_bounds__(256) void gemm_bt(const __hip_bfloat16* __restrict__ A,
                                               const __hip_bfloat16* __restrict__ Bm,
                                               const float* __restrict__ bias,
                                               void* __restrict__ Cv,
                                               int M, int N, int K) {
  __shared__ __align__(16) __hip_bfloat16 Asm[128 * 32];
  __shared__ __align__(16) __hip_bfloat16 Bsm[128 * 32];
  const int tid = threadIdx.x, wave = tid >> 6, lane = tid & 63;
  const int bm = blockIdx.y * 128, bn = blockIdx.x * 128;
  const int wm = (wave >> 1) * 64, wn = (wave & 1) * 64;
  f32x4 acc[4][4] = {};
  const int fr = lane & 15, fk = (lane >> 4) * 8;

  // staging: wave w, instr i covers rows w*32+i*16 .. +16; lane -> row base+lane/4, 16B chunk lane&3
  const int srow = wave * 32 + (lane >> 2);
  const size_t rowbytes = (size_t)K * 2;
  const char* Ag = (const char*)(A + (size_t)(bm + srow) * K) + (lane & 3) * 16;
  const char* Bg = (const char*)(Bm + (size_t)(bn + srow) * K) + (lane & 3) * 16;
  __hip_bfloat16* As0 = &Asm[(wave * 32) * 32];
  __hip_bfloat16* Bs0 = &Bsm[(wave * 32) * 32];

  for (int k0 = 0; k0 < K; k0 += 32) {
    const size_t kb = (size_t)k0 * 2;
    gload_lds16(Ag + kb, As0);
    gload_lds16(Ag + kb + 16 * rowbytes, &As0[16 * 32]);
    gload_lds16(Bg + kb, Bs0);
    gload_lds16(Bg + kb + 16 * rowbytes, &Bs0[16 * 32]);
    __syncthreads();
    bf16x8 af[4], bfr[4];
#pragma unroll
    for (int t = 0; t < 4; t++) af[t] = *(const bf16x8*)&Asm[(wm + t * 16 + fr) * 32 + fk];
#pragma unroll
    for (int t = 0; t < 4; t++) bfr[t] = *(const bf16x8*)&Bsm[(wn + t * 16 + fr) * 32 + fk];
#pragma unroll
    for (int i = 0; i < 4; i++)
#pragma unroll
      for (int j = 0; j < 4; j++)
        acc[i][j] = __builtin_amdgcn_mfma_f32_16x16x32_bf16(af[i], bfr[j], acc[i][j], 0, 0, 0);
    __syncthreads();
  }

  // epilogue: C layout col=lane&15, row=(lane>>4)*4+reg  [m89-verified]
  const int r0 = bm + wm + (lane >> 4) * 4;
  const int c0 = bn + wn + (lane & 15);
#pragma unroll
  for (int i = 0; i < 4; i++) {
#pragma unroll
    for (int j = 0; j < 4; j++) {
      const int col = c0 + j * 16;
      const float bv = bias[col];
#pragma unroll
      for (int r = 0; r < 4; r++) {
        const int row = r0 + i * 16 + r;
        float v = acc[i][j][r] + bv;
        if (OUT_BF16)
          ((__hip_bfloat16*)Cv)[(size_t)row * N + col] = __float2bfloat16(v);
        else
          ((float*)Cv)[(size_t)row * N + col] = v;
      }
    }
  }
}

// ---------------- flash attention ----------------
// grid: (S/64, B*H). 4 waves, each owns a 16-row q strip. KBLK=64, dh=128.
#define VTS 72  // padded Vt/P row stride (keeps ds_read_b128 16B-aligned, breaks worst conflicts)
__global__ __launch_bounds__(256) void flash_attn(const __hip_bfloat16* __restrict__ qkv,
                                                  __hip_bfloat16* __restrict__ y,
                                                  int S) {
  __shared__ __align__(16) char Ksm[64 * 256];            // K tile, XOR-swizzled 16B chunks
  __shared__ __align__(16) __hip_bfloat16 Vtsm[128 * VTS]; // V^T tile
  __shared__ __align__(16) __hip_bfloat16 Psm[4 * 16 * VTS];
  const int tid = threadIdx.x, wave = tid >> 6, lane = tid & 63;
  const int b = blockIdx.y >> 4, h = blockIdx.y & 15;
  const int q0 = blockIdx.x * 64;
  const size_t ldq = 6144;
  const __hip_bfloat16* Qb = qkv + (size_t)b * S * ldq + (size_t)h * 128;
  const __hip_bfloat16* Kb = Qb + 2048;
  const __hip_bfloat16* Vb = Qb + 4096;

  // Q strip -> registers (A-frag: row=lane&15, k=(lane>>4)*8)
  bf16x8 aq[4];
  {
    const int qrow = q0 + wave * 16 + (lane & 15);
    const __hip_bfloat16* qp = Qb + (size_t)qrow * ldq + (lane >> 4) * 8;
#pragma unroll
    for (int c = 0; c < 4; c++) aq[c] = *(const bf16x8*)(qp + c * 32);
  }

  float m_i[4] = {-1e30f, -1e30f, -1e30f, -1e30f};
  float l_i[4] = {0.f, 0.f, 0.f, 0.f};
  f32x4 oacc[8] = {};
  const int nT = q0 / 64 + 1;

  for (int t = 0; t < nT; ++t) {
    const int kv0 = t * 64;
    __syncthreads();  // prev-tile LDS reads drained
    // stage K: row-major [64][128], 16B chunks XOR-swizzled by row&7
#pragma unroll
    for (int i = 0; i < 4; i++) {
      int chunk = tid + i * 256;
      int row = chunk >> 4, c16 = chunk & 15;
      *(int4*)&Ksm[row * 256 + ((c16 ^ (row & 7)) * 16)] =
          *(const int4*)((const char*)(Kb + (size_t)(kv0 + row) * ldq) + c16 * 16);
    }
    // stage V transposed: Vt[d][j] = V[j][d]
#pragma unroll
    for (int i = 0; i < 32; i++) {
      int idx = i * 256 + tid;
      int d = idx & 127, j = idx >> 7;
      Vtsm[d * VTS + j] = Vb[(size_t)(kv0 + j) * ldq + d];
    }
    __syncthreads();

    // S = Q K^T (per wave: 16 rows x 64 cols)
    f32x4 sacc[4];
#pragma unroll
    for (int nf = 0; nf < 4; nf++) {
      f32x4 a = {0.f, 0.f, 0.f, 0.f};
      const int n = nf * 16 + (lane & 15);
#pragma unroll
      for (int c = 0; c < 4; c++) {
        int cc = c * 4 + (lane >> 4);
        bf16x8 kf = *(const bf16x8*)&Ksm[n * 256 + ((cc ^ (n & 7)) * 16)];
        a = __builtin_amdgcn_mfma_f32_16x16x32_bf16(aq[c], kf, a, 0, 0, 0);
      }
      sacc[nf] = a;
    }

    const float scale = 0.08838834764831845f;  // 1/sqrt(128)
    const bool diag = (kv0 == q0);
#pragma unroll
    for (int nf = 0; nf < 4; nf++)
#pragma unroll
      for (int r = 0; r < 4; r++) {
        float s = sacc[nf][r] * scale;
        if (diag) {
          int col = kv0 + nf * 16 + (lane & 15);
          int rowg = q0 + wave * 16 + (lane >> 4) * 4 + r;
          if (col > rowg) s = -1e30f;
        }
        sacc[nf][r] = s;
      }

    // wave-parallel row max / sum over the 16-lane group
    float corr[4];
#pragma unroll
    for (int r = 0; r < 4; r++) {
      float mx = fmaxf(fmaxf(sacc[0][r], sacc[1][r]), fmaxf(sacc[2][r], sacc[3][r]));
#pragma unroll
      for (int o = 1; o < 16; o <<= 1) mx = fmaxf(mx, __shfl_xor(mx, o, 64));
      float mnew = fmaxf(m_i[r], mx);
      corr[r] = __expf(m_i[r] - mnew);
      m_i[r] = mnew;
    }
#pragma unroll
    for (int r = 0; r < 4; r++) {
      float sum = 0.f;
#pragma unroll
      for (int nf = 0; nf < 4; nf++) {
        float p = __expf(sacc[nf][r] - m_i[r]);
        sacc[nf][r] = p;
        sum += p;
      }
#pragma unroll
      for (int o = 1; o < 16; o <<= 1) sum += __shfl_xor(sum, o, 64);
      l_i[r] = l_i[r] * corr[r] + sum;
    }
#pragma unroll
    for (int of = 0; of < 8; of++)
#pragma unroll
      for (int r = 0; r < 4; r++) oacc[of][r] *= corr[r];

    // P (C-layout) -> per-wave LDS -> A-frag layout
    __hip_bfloat16* Pw = &Psm[wave * 16 * VTS];
#pragma unroll
    for (int nf = 0; nf < 4; nf++)
#pragma unroll
      for (int r = 0; r < 4; r++)
        Pw[((lane >> 4) * 4 + r) * VTS + nf * 16 + (lane & 15)] = __float2bfloat16(sacc[nf][r]);
    asm volatile("s_waitcnt lgkmcnt(0)" ::: "memory");  // wave-internal RAW on Psm

    bf16x8 pa[2];
#pragma unroll
    for (int kc = 0; kc < 2; kc++)
      pa[kc] = *(const bf16x8*)&Pw[(lane & 15) * VTS + kc * 32 + (lane >> 4) * 8];
#pragma unroll
    for (int of = 0; of < 8; of++) {
#pragma unroll
      for (int kc = 0; kc < 2; kc++) {
        bf16x8 vb = *(const bf16x8*)&Vtsm[(of * 16 + (lane & 15)) * VTS + kc * 32 + (lane >> 4) * 8];
        oacc[of] = __builtin_amdgcn_mfma_f32_16x16x32_bf16(pa[kc], vb, oacc[of], 0, 0, 0);
      }
    }
  }

  // normalize + store y (bf16)
#pragma unroll
  for (int of = 0; of < 8; of++)
#pragma unroll
    for (int r = 0; r < 4; r++) {
      int rowg = q0 + wave * 16 + (lane >> 4) * 4 + r;
      int colg = h * 128 + of * 16 + (lane & 15);
      y[((size_t)b * S + rowg) * 2048 + colg] = __float2bfloat16(oacc[of][r] / l_i[r]);
    }
}

// ---------------- launch ----------------
extern "C" void kernel_launch(void* const* d_in, const int* in_sizes, int n_in,
                              void* d_out, int out_size, void* d_ws, size_t ws_size,
                              hipStream_t stream) {
  const float* x = (const float*)d_in[0];
  const float* qkv_w = (const float*)d_in[1];
  const float* qkv_b = (const float*)d_in[2];
  const float* out_w = (const float*)d_in[3];
  const float* out_b = (const float*)d_in[4];
  float* out = (float*)d_out;

  const int B = 4, S = 2048, D = 2048;
  const int M = B * S;  // 8192

  // workspace layout (202.4 MB total)
  char* ws = (char*)d_ws;
  __hip_bfloat16* xb   = (__hip_bfloat16*)(ws + 0);          // 33554432 B
  __hip_bfloat16* wqb  = (__hip_bfloat16*)(ws + 33554432);   // 25165824 B
  __hip_bfloat16* wob  = (__hip_bfloat16*)(ws + 58720256);   // 8388608 B
  __hip_bfloat16* qkvb = (__hip_bfloat16*)(ws + 67108864);   // 100663296 B
  __hip_bfloat16* yb   = (__hip_bfloat16*)(ws + 167772160);  // 33554432 B
  float* cosT          = (float*)(ws + 201326592);           // 524288 B
  float* sinT          = (float*)(ws + 201850880);           // 524288 B

  cast_f32_bf16<<<M * D / 4 / 256, 256, 0, stream>>>(x, xb, M * D / 4);
  cast_f32_bf16<<<3 * D * D / 4 / 256, 256, 0, stream>>>(qkv_w, wqb, 3 * D * D / 4);
  cast_f32_bf16<<<D * D / 4 / 256, 256, 0, stream>>>(out_w, wob, D * D / 4);
  rope_tables<<<S * 64 / 256, 256, 0, stream>>>(cosT, sinT, S);

  dim3 g1(3 * D / 128, M / 128);
  gemm_bt<1><<<g1, 256, 0, stream>>>(xb, wqb, qkv_b, (void*)qkvb, M, 3 * D, D);

  rope_apply<<<M * 1024 / 256, 256, 0, stream>>>(qkvb, cosT, sinT, M, S);

  dim3 g2(S / 64, B * 16);
  flash_attn<<<g2, 256, 0, stream>>>(qkvb, yb, S);

  dim3 g3(D / 128, M / 128);
  gemm_bt<0><<<g3, 256, 0, stream>>>(yb, wob, out_b, (void*)out, M, D, D);
}

// Round 3
// 897.891 us; speedup vs baseline: 1.1839x; 1.1839x over previous
//
#include <hip/hip_runtime.h>
#include <hip/hip_bf16.h>
#include <math.h>

typedef __bf16 bf16x8 __attribute__((ext_vector_type(8)));
typedef float f32x4 __attribute__((ext_vector_type(4)));

#define GPTR(x) ((const __attribute__((address_space(1))) void*)(x))
#define LPTR(x) ((__attribute__((address_space(3))) void*)(x))

__device__ __forceinline__ void gload_lds16(const void* g, void* l) {
  __builtin_amdgcn_global_load_lds(GPTR(g), LPTR(l), 16, 0, 0);
}

// ---------------- cast fp32 -> bf16, vectorized ----------------
__global__ __launch_bounds__(256) void cast_f32_bf16(const float* __restrict__ in,
                                                     __hip_bfloat16* __restrict__ out,
                                                     int n4) {
  int i = blockIdx.x * 256 + threadIdx.x;
  if (i >= n4) return;
  float4 v = ((const float4*)in)[i];
  __hip_bfloat16 t[4];
  t[0] = __float2bfloat16(v.x); t[1] = __float2bfloat16(v.y);
  t[2] = __float2bfloat16(v.z); t[3] = __float2bfloat16(v.w);
  ((uint2*)out)[i] = *(uint2*)t;
}

// ---------------- RoPE tables: cos/sin[s][j], j<64 ----------------
__global__ __launch_bounds__(256) void rope_tables(float* __restrict__ cosT,
                                                   float* __restrict__ sinT, int S) {
  int i = blockIdx.x * 256 + threadIdx.x;
  if (i >= S * 64) return;
  int j = i & 63, s = i >> 6;
  float freq = powf(10000.0f, -(float)(2 * j) * (1.0f / 128.0f));
  float a = (float)s * freq;
  cosT[i] = cosf(a);
  sinT[i] = sinf(a);
}

// ---------------- RoPE in-place, vectorized: 4 pairs (8 bf16) per thread ----
__global__ __launch_bounds__(256) void rope_apply(__hip_bfloat16* __restrict__ qkv,
                                                  const float* __restrict__ cosT,
                                                  const float* __restrict__ sinT) {
  int i = blockIdx.x * 256 + threadIdx.x;   // M*256 total
  int jc = i & 15;                          // 4-pair chunk within head
  int h = (i >> 4) & 15;
  int row = i >> 8;                         // b*S + s
  int s = row & 2047;                       // S = 2048
  float4 c4 = *(const float4*)&cosT[s * 64 + jc * 4];
  float4 s4 = *(const float4*)&sinT[s * 64 + jc * 4];
  size_t base = (size_t)row * 6144 + h * 128 + jc * 8;
#pragma unroll
  for (int half = 0; half < 2; half++) {
    __hip_bfloat16* p = qkv + base + half * 2048;   // q then k
    bf16x8 v = *(bf16x8*)p;
    bf16x8 o;
    float cc[4] = {c4.x, c4.y, c4.z, c4.w};
    float ss[4] = {s4.x, s4.y, s4.z, s4.w};
#pragma unroll
    for (int u = 0; u < 4; u++) {
      float x1 = (float)v[2 * u], x2 = (float)v[2 * u + 1];
      o[2 * u]     = (__bf16)(x1 * cc[u] - x2 * ss[u]);
      o[2 * u + 1] = (__bf16)(x1 * ss[u] + x2 * cc[u]);
    }
    *(bf16x8*)p = o;
  }
}

// ---------------- GEMM: C[M][N] = A[M][K] @ B[N][K]^T + bias ----------------
// m97 structure: 128x128 tile, BK=32, 4 waves (64x64 each), global_load_lds w16.
template <int OUT_BF16>
__global__ __launch_bounds__(256) void gemm_bt(const __hip_bfloat16* __restrict__ A,
                                               const __hip_bfloat16* __restrict__ Bm,
                                               const float* __restrict__ bias,
                                               void* __restrict__ Cv,
                                               int M, int N, int K) {
  __shared__ __align__(16) __hip_bfloat16 Asm[128 * 32];
  __shared__ __align__(16) __hip_bfloat16 Bsm[128 * 32];
  const int tid = threadIdx.x, wave = tid >> 6, lane = tid & 63;
  const int bm = blockIdx.y * 128, bn = blockIdx.x * 128;
  const int wm = (wave >> 1) * 64, wn = (wave & 1) * 64;
  f32x4 acc[4][4] = {};
  const int fr = lane & 15, fk = (lane >> 4) * 8;

  const int srow = wave * 32 + (lane >> 2);
  const size_t rowbytes = (size_t)K * 2;
  const char* Ag = (const char*)(A + (size_t)(bm + srow) * K) + (lane & 3) * 16;
  const char* Bg = (const char*)(Bm + (size_t)(bn + srow) * K) + (lane & 3) * 16;
  __hip_bfloat16* As0 = &Asm[(wave * 32) * 32];
  __hip_bfloat16* Bs0 = &Bsm[(wave * 32) * 32];

  for (int k0 = 0; k0 < K; k0 += 32) {
    const size_t kb = (size_t)k0 * 2;
    gload_lds16(Ag + kb, As0);
    gload_lds16(Ag + kb + 16 * rowbytes, &As0[16 * 32]);
    gload_lds16(Bg + kb, Bs0);
    gload_lds16(Bg + kb + 16 * rowbytes, &Bs0[16 * 32]);
    __syncthreads();
    bf16x8 af[4], bfr[4];
#pragma unroll
    for (int t = 0; t < 4; t++) af[t] = *(const bf16x8*)&Asm[(wm + t * 16 + fr) * 32 + fk];
#pragma unroll
    for (int t = 0; t < 4; t++) bfr[t] = *(const bf16x8*)&Bsm[(wn + t * 16 + fr) * 32 + fk];
#pragma unroll
    for (int i = 0; i < 4; i++)
#pragma unroll
      for (int j = 0; j < 4; j++)
        acc[i][j] = __builtin_amdgcn_mfma_f32_16x16x32_bf16(af[i], bfr[j], acc[i][j], 0, 0, 0);
    __syncthreads();
  }

  const int r0 = bm + wm + (lane >> 4) * 4;
  const int c0 = bn + wn + (lane & 15);
#pragma unroll
  for (int i = 0; i < 4; i++) {
#pragma unroll
    for (int j = 0; j < 4; j++) {
      const int col = c0 + j * 16;
      const float bv = bias[col];
#pragma unroll
      for (int r = 0; r < 4; r++) {
        const int row = r0 + i * 16 + r;
        float v = acc[i][j][r] + bv;
        if (OUT_BF16)
          ((__hip_bfloat16*)Cv)[(size_t)row * N + col] = __float2bfloat16(v);
        else
          ((float*)Cv)[(size_t)row * N + col] = v;
      }
    }
  }
}

// ---------------- flash attention ----------------
// grid: (S/128, B*H). 512 thr / 8 waves; each wave owns a 16-row q strip.
// KVBLK=64, dh=128. Register-prefetch staging: next tile's K/V global loads
// issue before compute of the current tile (latency hides under QK+PV).
#define VTS 72
__global__ __launch_bounds__(512, 4) void flash_attn(const __hip_bfloat16* __restrict__ qkv,
                                                     __hip_bfloat16* __restrict__ y,
                                                     int S) {
  __shared__ __align__(16) char Ksm[64 * 256];             // K, XOR-swizzled 16B chunks
  __shared__ __align__(16) __hip_bfloat16 Vtsm[128 * VTS]; // V^T
  __shared__ __align__(16) __hip_bfloat16 Psm[8 * 16 * VTS];
  const int tid = threadIdx.x, wave = tid >> 6, lane = tid & 63;
  const int b = blockIdx.y >> 4, h = blockIdx.y & 15;
  const int q0 = ((int)gridDim.x - 1 - (int)blockIdx.x) * 128;  // longest blocks first
  const size_t ldq = 6144;
  const __hip_bfloat16* Qb = qkv + (size_t)b * S * ldq + (size_t)h * 128;
  const __hip_bfloat16* Kb = Qb + 2048;
  const __hip_bfloat16* Vb = Qb + 4096;

  // Q strip -> registers (A-frag: row=lane&15, k=(lane>>4)*8)
  bf16x8 aq[4];
  {
    const int qrow = q0 + wave * 16 + (lane & 15);
    const __hip_bfloat16* qp = Qb + (size_t)qrow * ldq + (lane >> 4) * 8;
#pragma unroll
    for (int c = 0; c < 4; c++) aq[c] = *(const bf16x8*)(qp + c * 32);
  }

  float m_i[4] = {-1e30f, -1e30f, -1e30f, -1e30f};
  float l_i[4] = {0.f, 0.f, 0.f, 0.f};
  f32x4 oacc[8] = {};
  const int nT = q0 / 64 + 2;
  const int rmin = q0 + wave * 16, rmax = rmin + 15;
  const int vj = tid & 63;  // kv row this thread stages for V

  int4 kreg[2], vreg[2];
  // prologue: prefetch tile 0
#pragma unroll
  for (int i = 0; i < 2; i++) {
    int chunk = tid + i * 512, krow = chunk >> 4, kc16 = chunk & 15;
    kreg[i] = *(const int4*)((const char*)(Kb + (size_t)krow * ldq) + kc16 * 16);
    int dc = wave + 8 * i;
    vreg[i] = *(const int4*)(Vb + (size_t)vj * ldq + dc * 8);
  }

  for (int t = 0; t < nT; ++t) {
    const int kv0 = t * 64;
    __syncthreads();  // all waves done reading prev tile's LDS
    // ---- write staged regs to LDS ----
#pragma unroll
    for (int i = 0; i < 2; i++) {
      int chunk = tid + i * 512, krow = chunk >> 4, kc16 = chunk & 15;
      *(int4*)&Ksm[krow * 256 + ((kc16 ^ (krow & 7)) * 16)] = kreg[i];
      int dc = wave + 8 * i;
      const __hip_bfloat16* e = (const __hip_bfloat16*)&vreg[i];
#pragma unroll
      for (int u = 0; u < 8; u++) Vtsm[(dc * 8 + u) * VTS + vj] = e[u];  // lane-consecutive: conflict-free
    }
    __syncthreads();
    // ---- issue next tile's loads (overlap with compute below) ----
    if (t + 1 < nT) {
      const int nkv = kv0 + 64;
#pragma unroll
      for (int i = 0; i < 2; i++) {
        int chunk = tid + i * 512, krow = chunk >> 4, kc16 = chunk & 15;
        kreg[i] = *(const int4*)((const char*)(Kb + (size_t)(nkv + krow) * ldq) + kc16 * 16);
        int dc = wave + 8 * i;
        vreg[i] = *(const int4*)(Vb + (size_t)(nkv + vj) * ldq + dc * 8);
      }
    }
    if (kv0 > rmax) continue;  // wave fully masked for this tile (barriers already done)

    // ---- S = Q K^T (16 rows x 64 cols per wave) ----
    f32x4 sacc[4];
#pragma unroll
    for (int nf = 0; nf < 4; nf++) {
      f32x4 a = {0.f, 0.f, 0.f, 0.f};
      const int n = nf * 16 + (lane & 15);
#pragma unroll
      for (int c = 0; c < 4; c++) {
        int cc = c * 4 + (lane >> 4);
        bf16x8 kf = *(const bf16x8*)&Ksm[n * 256 + ((cc ^ (n & 7)) * 16)];
        a = __builtin_amdgcn_mfma_f32_16x16x32_bf16(aq[c], kf, a, 0, 0, 0);
      }
      sacc[nf] = a;
    }

    const float scale = 0.08838834764831845f;  // 1/sqrt(128)
    const bool need_mask = (kv0 + 63 > rmin);
#pragma unroll
    for (int nf = 0; nf < 4; nf++)
#pragma unroll
      for (int r = 0; r < 4; r++) {
        float s = sacc[nf][r] * scale;
        if (need_mask) {
          int col = kv0 + nf * 16 + (lane & 15);
          int rowg = rmin + (lane >> 4) * 4 + r;
          if (col > rowg) s = -1e30f;
        }
        sacc[nf][r] = s;
      }

    // wave-parallel row max / sum over the 16-lane group
    float corr[4];
#pragma unroll
    for (int r = 0; r < 4; r++) {
      float mx = fmaxf(fmaxf(sacc[0][r], sacc[1][r]), fmaxf(sacc[2][r], sacc[3][r]));
#pragma unroll
      for (int o = 1; o < 16; o <<= 1) mx = fmaxf(mx, __shfl_xor(mx, o, 64));
      float mnew = fmaxf(m_i[r], mx);
      corr[r] = __expf(m_i[r] - mnew);
      m_i[r] = mnew;
    }
#pragma unroll
    for (int r = 0; r < 4; r++) {
      float sum = 0.f;
#pragma unroll
      for (int nf = 0; nf < 4; nf++) {
        float p = __expf(sacc[nf][r] - m_i[r]);
        sacc[nf][r] = p;
        sum += p;
      }
#pragma unroll
      for (int o = 1; o < 16; o <<= 1) sum += __shfl_xor(sum, o, 64);
      l_i[r] = l_i[r] * corr[r] + sum;
    }
#pragma unroll
    for (int of = 0; of < 8; of++)
#pragma unroll
      for (int r = 0; r < 4; r++) oacc[of][r] *= corr[r];

    // P (C-layout) -> per-wave LDS -> A-frag layout
    __hip_bfloat16* Pw = &Psm[wave * 16 * VTS];
#pragma unroll
    for (int nf = 0; nf < 4; nf++)
#pragma unroll
      for (int r = 0; r < 4; r++)
        Pw[((lane >> 4) * 4 + r) * VTS + nf * 16 + (lane & 15)] = __float2bfloat16(sacc[nf][r]);
    asm volatile("s_waitcnt lgkmcnt(0)" ::: "memory");  // wave-internal RAW on Psm

    bf16x8 pa[2];
#pragma unroll
    for (int kc = 0; kc < 2; kc++)
      pa[kc] = *(const bf16x8*)&Pw[(lane & 15) * VTS + kc * 32 + (lane >> 4) * 8];
#pragma unroll
    for (int of = 0; of < 8; of++) {
#pragma unroll
      for (int kc = 0; kc < 2; kc++) {
        bf16x8 vb = *(const bf16x8*)&Vtsm[(of * 16 + (lane & 15)) * VTS + kc * 32 + (lane >> 4) * 8];
        oacc[of] = __builtin_amdgcn_mfma_f32_16x16x32_bf16(pa[kc], vb, oacc[of], 0, 0, 0);
      }
    }
  }

  // normalize + store y (bf16)
#pragma unroll
  for (int of = 0; of < 8; of++)
#pragma unroll
    for (int r = 0; r < 4; r++) {
      int rowg = q0 + wave * 16 + (lane >> 4) * 4 + r;
      int colg = h * 128 + of * 16 + (lane & 15);
      y[((size_t)b * S + rowg) * 2048 + colg] = __float2bfloat16(oacc[of][r] / l_i[r]);
    }
}

// ---------------- launch ----------------
extern "C" void kernel_launch(void* const* d_in, const int* in_sizes, int n_in,
                              void* d_out, int out_size, void* d_ws, size_t ws_size,
                              hipStream_t stream) {
  const float* x = (const float*)d_in[0];
  const float* qkv_w = (const float*)d_in[1];
  const float* qkv_b = (const float*)d_in[2];
  const float* out_w = (const float*)d_in[3];
  const float* out_b = (const float*)d_in[4];
  float* out = (float*)d_out;

  const int B = 4, S = 2048, D = 2048;
  const int M = B * S;  // 8192

  char* ws = (char*)d_ws;
  __hip_bfloat16* xb   = (__hip_bfloat16*)(ws + 0);
  __hip_bfloat16* wqb  = (__hip_bfloat16*)(ws + 33554432);
  __hip_bfloat16* wob  = (__hip_bfloat16*)(ws + 58720256);
  __hip_bfloat16* qkvb = (__hip_bfloat16*)(ws + 67108864);
  __hip_bfloat16* yb   = (__hip_bfloat16*)(ws + 167772160);
  float* cosT          = (float*)(ws + 201326592);
  float* sinT          = (float*)(ws + 201850880);

  cast_f32_bf16<<<M * D / 4 / 256, 256, 0, stream>>>(x, xb, M * D / 4);
  cast_f32_bf16<<<3 * D * D / 4 / 256, 256, 0, stream>>>(qkv_w, wqb, 3 * D * D / 4);
  cast_f32_bf16<<<D * D / 4 / 256, 256, 0, stream>>>(out_w, wob, D * D / 4);
  rope_tables<<<S * 64 / 256, 256, 0, stream>>>(cosT, sinT, S);

  dim3 g1(3 * D / 128, M / 128);
  gemm_bt<1><<<g1, 256, 0, stream>>>(xb, wqb, qkv_b, (void*)qkvb, M, 3 * D, D);

  rope_apply<<<M, 256, 0, stream>>>(qkvb, cosT, sinT);

  dim3 g2(S / 128, B * 16);
  flash_attn<<<g2, 512, 0, stream>>>(qkvb, yb, S);

  dim3 g3(D / 128, M / 128);
  gemm_bt<0><<<g3, 256, 0, stream>>>(yb, wob, out_b, (void*)out, M, D, D);
}

// Round 5
// 830.899 us; speedup vs baseline: 1.2793x; 1.0806x over previous
//
#include <hip/hip_runtime.h>
#include <hip/hip_bf16.h>
#include <math.h>

typedef __bf16 bf16x8 __attribute__((ext_vector_type(8)));
typedef float f32x4 __attribute__((ext_vector_type(4)));

#define GPTR(x) ((const __attribute__((address_space(1))) void*)(x))
#define LPTR(x) ((__attribute__((address_space(3))) void*)(x))

__device__ __forceinline__ void gload_lds16(const void* g, void* l) {
  __builtin_amdgcn_global_load_lds(GPTR(g), LPTR(l), 16, 0, 0);
}

// ---------------- cast fp32 -> bf16, vectorized ----------------
__global__ __launch_bounds__(256) void cast_f32_bf16(const float* __restrict__ in,
                                                     __hip_bfloat16* __restrict__ out,
                                                     int n4) {
  int i = blockIdx.x * 256 + threadIdx.x;
  if (i >= n4) return;
  float4 v = ((const float4*)in)[i];
  __hip_bfloat16 t[4];
  t[0] = __float2bfloat16(v.x); t[1] = __float2bfloat16(v.y);
  t[2] = __float2bfloat16(v.z); t[3] = __float2bfloat16(v.w);
  ((uint2*)out)[i] = *(uint2*)t;
}

// ---------------- RoPE tables: cos/sin[s][j], j<64 ----------------
__global__ __launch_bounds__(256) void rope_tables(float* __restrict__ cosT,
                                                   float* __restrict__ sinT, int S) {
  int i = blockIdx.x * 256 + threadIdx.x;
  if (i >= S * 64) return;
  int j = i & 63, s = i >> 6;
  float freq = powf(10000.0f, -(float)(2 * j) * (1.0f / 128.0f));
  float a = (float)s * freq;
  cosT[i] = cosf(a);
  sinT[i] = sinf(a);
}

// ---------------- RoPE in-place, vectorized: 4 pairs (8 bf16) per thread ----
__global__ __launch_bounds__(256) void rope_apply(__hip_bfloat16* __restrict__ qkv,
                                                  const float* __restrict__ cosT,
                                                  const float* __restrict__ sinT) {
  int i = blockIdx.x * 256 + threadIdx.x;   // M*256 total
  int jc = i & 15;                          // 4-pair chunk within head
  int h = (i >> 4) & 15;
  int row = i >> 8;                         // b*S + s
  int s = row & 2047;                       // S = 2048
  float4 c4 = *(const float4*)&cosT[s * 64 + jc * 4];
  float4 s4 = *(const float4*)&sinT[s * 64 + jc * 4];
  size_t base = (size_t)row * 6144 + h * 128 + jc * 8;
#pragma unroll
  for (int half = 0; half < 2; half++) {
    __hip_bfloat16* p = qkv + base + half * 2048;   // q then k
    bf16x8 v = *(bf16x8*)p;
    bf16x8 o;
    float cc[4] = {c4.x, c4.y, c4.z, c4.w};
    float ss[4] = {s4.x, s4.y, s4.z, s4.w};
#pragma unroll
    for (int u = 0; u < 4; u++) {
      float x1 = (float)v[2 * u], x2 = (float)v[2 * u + 1];
      o[2 * u]     = (__bf16)(x1 * cc[u] - x2 * ss[u]);
      o[2 * u + 1] = (__bf16)(x1 * ss[u] + x2 * cc[u]);
    }
    *(bf16x8*)p = o;
  }
}

// ---------------- GEMM: C[M][N] = A[M][K] @ B[N][K]^T + bias ----------------
// m97 structure: 128x128 tile, BK=32, 4 waves (64x64 each), global_load_lds w16.
template <int OUT_BF16>
__global__ __launch_bounds__(256) void gemm_bt(const __hip_bfloat16* __restrict__ A,
                                               const __hip_bfloat16* __restrict__ Bm,
                                               const float* __restrict__ bias,
                                               void* __restrict__ Cv,
                                               int M, int N, int K) {
  __shared__ __align__(16) __hip_bfloat16 Asm[128 * 32];
  __shared__ __align__(16) __hip_bfloat16 Bsm[128 * 32];
  const int tid = threadIdx.x, wave = tid >> 6, lane = tid & 63;
  const int bm = blockIdx.y * 128, bn = blockIdx.x * 128;
  const int wm = (wave >> 1) * 64, wn = (wave & 1) * 64;
  f32x4 acc[4][4] = {};
  const int fr = lane & 15, fk = (lane >> 4) * 8;

  const int srow = wave * 32 + (lane >> 2);
  const size_t rowbytes = (size_t)K * 2;
  const char* Ag = (const char*)(A + (size_t)(bm + srow) * K) + (lane & 3) * 16;
  const char* Bg = (const char*)(Bm + (size_t)(bn + srow) * K) + (lane & 3) * 16;
  __hip_bfloat16* As0 = &Asm[(wave * 32) * 32];
  __hip_bfloat16* Bs0 = &Bsm[(wave * 32) * 32];

  for (int k0 = 0; k0 < K; k0 += 32) {
    const size_t kb = (size_t)k0 * 2;
    gload_lds16(Ag + kb, As0);
    gload_lds16(Ag + kb + 16 * rowbytes, &As0[16 * 32]);
    gload_lds16(Bg + kb, Bs0);
    gload_lds16(Bg + kb + 16 * rowbytes, &Bs0[16 * 32]);
    __syncthreads();
    bf16x8 af[4], bfr[4];
#pragma unroll
    for (int t = 0; t < 4; t++) af[t] = *(const bf16x8*)&Asm[(wm + t * 16 + fr) * 32 + fk];
#pragma unroll
    for (int t = 0; t < 4; t++) bfr[t] = *(const bf16x8*)&Bsm[(wn + t * 16 + fr) * 32 + fk];
#pragma unroll
    for (int i = 0; i < 4; i++)
#pragma unroll
      for (int j = 0; j < 4; j++)
        acc[i][j] = __builtin_amdgcn_mfma_f32_16x16x32_bf16(af[i], bfr[j], acc[i][j], 0, 0, 0);
    __syncthreads();
  }

  const int r0 = bm + wm + (lane >> 4) * 4;
  const int c0 = bn + wn + (lane & 15);
#pragma unroll
  for (int i = 0; i < 4; i++) {
#pragma unroll
    for (int j = 0; j < 4; j++) {
      const int col = c0 + j * 16;
      const float bv = bias[col];
#pragma unroll
      for (int r = 0; r < 4; r++) {
        const int row = r0 + i * 16 + r;
        float v = acc[i][j][r] + bv;
        if (OUT_BF16)
          ((__hip_bfloat16*)Cv)[(size_t)row * N + col] = __float2bfloat16(v);
        else
          ((float*)Cv)[(size_t)row * N + col] = v;
      }
    }
  }
}

// ---------------- flash attention (swapped-QK^T, lane-local softmax) --------
// grid: (S/128, B*H). 512 thr / 8 waves; wave owns 16 q rows; KVBLK=64, dh=128.
// S^T = mfma(K,Q): lane holds 16 scores of q-row (lane&15) -> softmax in-lane
// (+2 shfl). PV computes O^T = mfma(Vt, P); the kv-permutation of P's held
// layout is absorbed into Vt's LDS column order -> zero P data movement.
#define VTS 72
__global__ __launch_bounds__(512, 4) void flash_attn(const __hip_bfloat16* __restrict__ qkv,
                                                     __hip_bfloat16* __restrict__ y,
                                                     int S) {
  __shared__ __align__(16) char Ksm[64 * 256];             // K, XOR-swizzled 16B chunks
  __shared__ __align__(16) __hip_bfloat16 Vts[128 * VTS];  // V^T, kv-permuted columns
  const int tid = threadIdx.x, wave = tid >> 6, lane = tid & 63;
  const int l15 = lane & 15, g = lane >> 4;
  const int b = blockIdx.y >> 4, h = blockIdx.y & 15;
  const int q0 = ((int)gridDim.x - 1 - (int)blockIdx.x) * 128;  // longest first
  const size_t ldq = 6144;
  const __hip_bfloat16* Qb = qkv + (size_t)b * S * ldq + (size_t)h * 128;
  const __hip_bfloat16* Kb = Qb + 2048;
  const __hip_bfloat16* Vb = Qb + 4096;

  const int qr = q0 + wave * 16 + l15;   // this lane's q row (global)
  const int rmin = q0 + wave * 16, rmax = rmin + 15;

  // Q -> B-frag regs: col=q=lane&15, k-slice=(lane>>4)*8 (+32 per MFMA step)
  bf16x8 aq[4];
  {
    const __hip_bfloat16* qp = Qb + (size_t)qr * ldq + g * 8;
#pragma unroll
    for (int c = 0; c < 4; c++) aq[c] = *(const bf16x8*)(qp + c * 32);
  }

  float m_r = -1e30f, l_r = 0.f;
  f32x4 oacc[8] = {};   // O^T: row d = of*16+g*4+r, col q = l15
  const int nT = q0 / 64 + 2;

  // V store column permutation: kv (=lane) -> pos so that PV A-frag reads are
  // contiguous b128 at [kc*32 + g*8].  pos = (m>>1)*32 + gv*8 + (m&1)*4 + r,
  // m=kv>>4, gv=(kv>>2)&3, r=kv&3.
  const int posj = ((lane >> 5) << 5) | ((((lane >> 2) & 3)) << 3) |
                   (((lane >> 4) & 1) << 2) | (lane & 3);

  int4 kreg[2], vreg[2];
#pragma unroll
  for (int i = 0; i < 2; i++) {   // prologue: prefetch tile 0
    int chunk = tid + i * 512, krow = chunk >> 4, kc16 = chunk & 15;
    kreg[i] = *(const int4*)((const char*)(Kb + (size_t)krow * ldq) + kc16 * 16);
    int dc = wave + 8 * i;
    vreg[i] = *(const int4*)(Vb + (size_t)lane * ldq + dc * 8);
  }

  for (int t = 0; t < nT; ++t) {
    const int kv0 = t * 64;
    __syncthreads();  // all waves done reading prev tile's LDS
    // ---- write staged regs to LDS ----
#pragma unroll
    for (int i = 0; i < 2; i++) {
      int chunk = tid + i * 512, krow = chunk >> 4, kc16 = chunk & 15;
      *(int4*)&Ksm[krow * 256 + ((kc16 ^ (krow & 7)) * 16)] = kreg[i];
      int dc = wave + 8 * i;
      const __hip_bfloat16* e = (const __hip_bfloat16*)&vreg[i];
#pragma unroll
      for (int u = 0; u < 8; u++) Vts[(dc * 8 + u) * VTS + posj] = e[u];
    }
    __syncthreads();
    // ---- issue next tile's loads (overlap with compute below) ----
    if (t + 1 < nT) {
      const int nkv = kv0 + 64;
#pragma unroll
      for (int i = 0; i < 2; i++) {
        int chunk = tid + i * 512, krow = chunk >> 4, kc16 = chunk & 15;
        kreg[i] = *(const int4*)((const char*)(Kb + (size_t)(nkv + krow) * ldq) + kc16 * 16);
        int dc = wave + 8 * i;
        vreg[i] = *(const int4*)(Vb + (size_t)(nkv + lane) * ldq + dc * 8);
      }
    }
    if (kv0 > rmax) continue;  // wave fully masked (barriers already done)

    // ---- S^T = K Q^T: rows kv = nf*16+g*4+r (regs), cols q = l15 ----
    f32x4 sacc[4];
#pragma unroll
    for (int nf = 0; nf < 4; nf++) {
      f32x4 a = {0.f, 0.f, 0.f, 0.f};
      const int n = nf * 16 + l15;  // kv row index for the A-frag read
#pragma unroll
      for (int c = 0; c < 4; c++) {
        int cc = c * 4 + g;
        bf16x8 kf = *(const bf16x8*)&Ksm[n * 256 + ((cc ^ (n & 7)) * 16)];
        a = __builtin_amdgcn_mfma_f32_16x16x32_bf16(kf, aq[c], a, 0, 0, 0);
      }
      sacc[nf] = a;
    }

    // ---- causal mask (unscaled scores) ----
    if (kv0 + 63 > rmin) {
#pragma unroll
      for (int nf = 0; nf < 4; nf++)
#pragma unroll
        for (int r = 0; r < 4; r++)
          if (kv0 + nf * 16 + g * 4 + r > qr) sacc[nf][r] = -3e38f;
    }

    // ---- lane-local softmax (scale folded into exp2) ----
    const float t2e = 0.12751744f;  // (1/sqrt(128)) * log2(e)
    float mx = sacc[0][0];
#pragma unroll
    for (int nf = 0; nf < 4; nf++)
#pragma unroll
      for (int r = 0; r < 4; r++) mx = fmaxf(mx, sacc[nf][r]);
    mx = fmaxf(mx, __shfl_xor(mx, 16, 64));
    mx = fmaxf(mx, __shfl_xor(mx, 32, 64));
    float mnew = fmaxf(m_r, mx);
    float corr = __builtin_amdgcn_exp2f((m_r - mnew) * t2e);
    m_r = mnew;
    float sum = 0.f;
#pragma unroll
    for (int nf = 0; nf < 4; nf++)
#pragma unroll
      for (int r = 0; r < 4; r++) {
        float pv = __builtin_amdgcn_exp2f((sacc[nf][r] - m_r) * t2e);
        sacc[nf][r] = pv;
        sum += pv;
      }
    sum += __shfl_xor(sum, 16, 64);
    sum += __shfl_xor(sum, 32, 64);
    l_r = l_r * corr + sum;
#pragma unroll
    for (int of = 0; of < 8; of++)
#pragma unroll
      for (int r = 0; r < 4; r++) oacc[of][r] *= corr;

    // ---- pack P -> B-frag (pure in-lane; kv order matches Vts permutation) --
    bf16x8 pa0, pa1;
#pragma unroll
    for (int r = 0; r < 4; r++) {
      pa0[r]     = (__bf16)sacc[0][r];
      pa0[r + 4] = (__bf16)sacc[1][r];
      pa1[r]     = (__bf16)sacc[2][r];
      pa1[r + 4] = (__bf16)sacc[3][r];
    }

    // ---- O^T += V^T P ----
#pragma unroll
    for (int of = 0; of < 8; of++) {
      const int vrow = of * 16 + l15;
      bf16x8 v0 = *(const bf16x8*)&Vts[vrow * VTS + g * 8];
      bf16x8 v1 = *(const bf16x8*)&Vts[vrow * VTS + 32 + g * 8];
      oacc[of] = __builtin_amdgcn_mfma_f32_16x16x32_bf16(v0, pa0, oacc[of], 0, 0, 0);
      oacc[of] = __builtin_amdgcn_mfma_f32_16x16x32_bf16(v1, pa1, oacc[of], 0, 0, 0);
    }
  }

  // ---- normalize + store y: lane owns q-row l15, d = of*16+g*4+(0..3) ----
  const float inv = 1.0f / l_r;
  __hip_bfloat16* yp = y + ((size_t)b * S + qr) * 2048 + h * 128;
#pragma unroll
  for (int of = 0; of < 8; of++) {
    __hip_bfloat16 o4[4];
#pragma unroll
    for (int r = 0; r < 4; r++) o4[r] = __float2bfloat16(oacc[of][r] * inv);
    *(uint2*)&yp[of * 16 + g * 4] = *(uint2*)o4;
  }
}

// ---------------- launch ----------------
extern "C" void kernel_launch(void* const* d_in, const int* in_sizes, int n_in,
                              void* d_out, int out_size, void* d_ws, size_t ws_size,
                              hipStream_t stream) {
  const float* x = (const float*)d_in[0];
  const float* qkv_w = (const float*)d_in[1];
  const float* qkv_b = (const float*)d_in[2];
  const float* out_w = (const float*)d_in[3];
  const float* out_b = (const float*)d_in[4];
  float* out = (float*)d_out;

  const int B = 4, S = 2048, D = 2048;
  const int M = B * S;  // 8192

  char* ws = (char*)d_ws;
  __hip_bfloat16* xb   = (__hip_bfloat16*)(ws + 0);
  __hip_bfloat16* wqb  = (__hip_bfloat16*)(ws + 33554432);
  __hip_bfloat16* wob  = (__hip_bfloat16*)(ws + 58720256);
  __hip_bfloat16* qkvb = (__hip_bfloat16*)(ws + 67108864);
  __hip_bfloat16* yb   = (__hip_bfloat16*)(ws + 167772160);
  float* cosT          = (float*)(ws + 201326592);
  float* sinT          = (float*)(ws + 201850880);

  cast_f32_bf16<<<M * D / 4 / 256, 256, 0, stream>>>(x, xb, M * D / 4);
  cast_f32_bf16<<<3 * D * D / 4 / 256, 256, 0, stream>>>(qkv_w, wqb, 3 * D * D / 4);
  cast_f32_bf16<<<D * D / 4 / 256, 256, 0, stream>>>(out_w, wob, D * D / 4);
  rope_tables<<<S * 64 / 256, 256, 0, stream>>>(cosT, sinT, S);

  dim3 g1(3 * D / 128, M / 128);
  gemm_bt<1><<<g1, 256, 0, stream>>>(xb, wqb, qkv_b, (void*)qkvb, M, 3 * D, D);

  rope_apply<<<M, 256, 0, stream>>>(qkvb, cosT, sinT);

  dim3 g2(S / 128, B * 16);
  flash_attn<<<g2, 512, 0, stream>>>(qkvb, yb, S);

  dim3 g3(D / 128, M / 128);
  gemm_bt<0><<<g3, 256, 0, stream>>>(yb, wob, out_b, (void*)out, M, D, D);
}

// Round 6
// 724.831 us; speedup vs baseline: 1.4665x; 1.1463x over previous
//
#include <hip/hip_runtime.h>
#include <hip/hip_bf16.h>
#include <math.h>

typedef __bf16 bf16x8 __attribute__((ext_vector_type(8)));
typedef float f32x4 __attribute__((ext_vector_type(4)));

#define GPTR(x) ((const __attribute__((address_space(1))) void*)(x))
#define LPTR(x) ((__attribute__((address_space(3))) void*)(x))

__device__ __forceinline__ void gload_lds16(const void* g, void* l) {
  __builtin_amdgcn_global_load_lds(GPTR(g), LPTR(l), 16, 0, 0);
}

// ---------------- cast fp32 -> bf16, vectorized ----------------
__global__ __launch_bounds__(256) void cast_f32_bf16(const float* __restrict__ in,
                                                     __hip_bfloat16* __restrict__ out,
                                                     int n4) {
  int i = blockIdx.x * 256 + threadIdx.x;
  if (i >= n4) return;
  float4 v = ((const float4*)in)[i];
  __hip_bfloat16 t[4];
  t[0] = __float2bfloat16(v.x); t[1] = __float2bfloat16(v.y);
  t[2] = __float2bfloat16(v.z); t[3] = __float2bfloat16(v.w);
  ((uint2*)out)[i] = *(uint2*)t;
}

// ---------------- RoPE tables: cos/sin[s][j], j<64 ----------------
__global__ __launch_bounds__(256) void rope_tables(float* __restrict__ cosT,
                                                   float* __restrict__ sinT, int S) {
  int i = blockIdx.x * 256 + threadIdx.x;
  if (i >= S * 64) return;
  int j = i & 63, s = i >> 6;
  float freq = powf(10000.0f, -(float)(2 * j) * (1.0f / 128.0f));
  float a = (float)s * freq;
  cosT[i] = cosf(a);
  sinT[i] = sinf(a);
}

// ---------------- RoPE in-place, vectorized: 4 pairs (8 bf16) per thread ----
__global__ __launch_bounds__(256) void rope_apply(__hip_bfloat16* __restrict__ qkv,
                                                  const float* __restrict__ cosT,
                                                  const float* __restrict__ sinT) {
  int i = blockIdx.x * 256 + threadIdx.x;   // M*256 total
  int jc = i & 15;                          // 4-pair chunk within head
  int h = (i >> 4) & 15;
  int row = i >> 8;                         // b*S + s
  int s = row & 2047;                       // S = 2048
  float4 c4 = *(const float4*)&cosT[s * 64 + jc * 4];
  float4 s4 = *(const float4*)&sinT[s * 64 + jc * 4];
  size_t base = (size_t)row * 6144 + h * 128 + jc * 8;
#pragma unroll
  for (int half = 0; half < 2; half++) {
    __hip_bfloat16* p = qkv + base + half * 2048;   // q then k
    bf16x8 v = *(bf16x8*)p;
    bf16x8 o;
    float cc[4] = {c4.x, c4.y, c4.z, c4.w};
    float ss[4] = {s4.x, s4.y, s4.z, s4.w};
#pragma unroll
    for (int u = 0; u < 4; u++) {
      float x1 = (float)v[2 * u], x2 = (float)v[2 * u + 1];
      o[2 * u]     = (__bf16)(x1 * cc[u] - x2 * ss[u]);
      o[2 * u + 1] = (__bf16)(x1 * ss[u] + x2 * cc[u]);
    }
    *(bf16x8*)p = o;
  }
}

// ---------------- GEMM: C[M][N] = A[M][K] @ B[N][K]^T + bias ----------------
// m97 structure: 128x128 tile, BK=32, 4 waves (64x64 each), global_load_lds w16.
template <int OUT_BF16>
__global__ __launch_bounds__(256) void gemm_bt(const __hip_bfloat16* __restrict__ A,
                                               const __hip_bfloat16* __restrict__ Bm,
                                               const float* __restrict__ bias,
                                               void* __restrict__ Cv,
                                               int M, int N, int K) {
  __shared__ __align__(16) __hip_bfloat16 Asm[128 * 32];
  __shared__ __align__(16) __hip_bfloat16 Bsm[128 * 32];
  const int tid = threadIdx.x, wave = tid >> 6, lane = tid & 63;
  const int bm = blockIdx.y * 128, bn = blockIdx.x * 128;
  const int wm = (wave >> 1) * 64, wn = (wave & 1) * 64;
  f32x4 acc[4][4] = {};
  const int fr = lane & 15, fk = (lane >> 4) * 8;

  const int srow = wave * 32 + (lane >> 2);
  const size_t rowbytes = (size_t)K * 2;
  const char* Ag = (const char*)(A + (size_t)(bm + srow) * K) + (lane & 3) * 16;
  const char* Bg = (const char*)(Bm + (size_t)(bn + srow) * K) + (lane & 3) * 16;
  __hip_bfloat16* As0 = &Asm[(wave * 32) * 32];
  __hip_bfloat16* Bs0 = &Bsm[(wave * 32) * 32];

  for (int k0 = 0; k0 < K; k0 += 32) {
    const size_t kb = (size_t)k0 * 2;
    gload_lds16(Ag + kb, As0);
    gload_lds16(Ag + kb + 16 * rowbytes, &As0[16 * 32]);
    gload_lds16(Bg + kb, Bs0);
    gload_lds16(Bg + kb + 16 * rowbytes, &Bs0[16 * 32]);
    __syncthreads();
    bf16x8 af[4], bfr[4];
#pragma unroll
    for (int t = 0; t < 4; t++) af[t] = *(const bf16x8*)&Asm[(wm + t * 16 + fr) * 32 + fk];
#pragma unroll
    for (int t = 0; t < 4; t++) bfr[t] = *(const bf16x8*)&Bsm[(wn + t * 16 + fr) * 32 + fk];
#pragma unroll
    for (int i = 0; i < 4; i++)
#pragma unroll
      for (int j = 0; j < 4; j++)
        acc[i][j] = __builtin_amdgcn_mfma_f32_16x16x32_bf16(af[i], bfr[j], acc[i][j], 0, 0, 0);
    __syncthreads();
  }

  const int r0 = bm + wm + (lane >> 4) * 4;
  const int c0 = bn + wn + (lane & 15);
#pragma unroll
  for (int i = 0; i < 4; i++) {
#pragma unroll
    for (int j = 0; j < 4; j++) {
      const int col = c0 + j * 16;
      const float bv = bias[col];
#pragma unroll
      for (int r = 0; r < 4; r++) {
        const int row = r0 + i * 16 + r;
        float v = acc[i][j][r] + bv;
        if (OUT_BF16)
          ((__hip_bfloat16*)Cv)[(size_t)row * N + col] = __float2bfloat16(v);
        else
          ((float*)Cv)[(size_t)row * N + col] = v;
      }
    }
  }
}

// ---------------- flash attention (swapped-QK^T, paired uniform blocks) -----
// grid: (8, B*H). Block (pi,bh) processes q-tiles (15-pi) then (pi): every
// block does exactly 34 KV-tiles -> zero tail, sustained occupancy.
// 512 thr / 8 waves; wave owns 16 q rows; KVBLK=64, dh=128.
// S^T = mfma(K,Q): lane holds 16 scores of q-row (lane&15) -> softmax in-lane
// (+2 shfl). PV computes O^T = mfma(Vt, P); the kv-permutation of P's held
// layout is absorbed into Vt's LDS column order -> zero P data movement.
#define VTS 72
__global__ __launch_bounds__(512, 4) void flash_attn(const __hip_bfloat16* __restrict__ qkv,
                                                     __hip_bfloat16* __restrict__ y,
                                                     int S) {
  __shared__ __align__(16) char Ksm[64 * 256];             // K, XOR-swizzled 16B chunks
  __shared__ __align__(16) __hip_bfloat16 Vts[128 * VTS];  // V^T, kv-permuted columns
  const int tid = threadIdx.x, wave = tid >> 6, lane = tid & 63;
  const int l15 = lane & 15, g = lane >> 4;
  const int b = blockIdx.y >> 4, h = blockIdx.y & 15;
  const int pi = blockIdx.x;  // 0..7
  const size_t ldq = 6144;
  const __hip_bfloat16* Qb = qkv + (size_t)b * S * ldq + (size_t)h * 128;
  const __hip_bfloat16* Kb = Qb + 2048;
  const __hip_bfloat16* Vb = Qb + 4096;

  // V store column permutation: kv (=lane) -> pos so that PV A-frag reads are
  // contiguous b128 at [kc*32 + g*8].
  const int posj = ((lane >> 5) << 5) | ((((lane >> 2) & 3)) << 3) |
                   (((lane >> 4) & 1) << 2) | (lane & 3);

  for (int pass = 0; pass < 2; ++pass) {
    const int qt = pass == 0 ? (15 - pi) : pi;   // long tile first
    const int q0 = qt * 128;
    const int qr = q0 + wave * 16 + l15;   // this lane's q row (global)
    const int rmin = q0 + wave * 16, rmax = rmin + 15;

    // Q -> B-frag regs: col=q=lane&15, k-slice=(lane>>4)*8 (+32 per MFMA step)
    bf16x8 aq[4];
    {
      const __hip_bfloat16* qp = Qb + (size_t)qr * ldq + g * 8;
#pragma unroll
      for (int c = 0; c < 4; c++) aq[c] = *(const bf16x8*)(qp + c * 32);
    }

    float m_r = -1e30f, l_r = 0.f;
    f32x4 oacc[8] = {};   // O^T: row d = of*16+g*4+r, col q = l15
    const int nT = q0 / 64 + 2;

    int4 kreg[2], vreg[2];
#pragma unroll
    for (int i = 0; i < 2; i++) {   // prologue: prefetch tile 0
      int chunk = tid + i * 512, krow = chunk >> 4, kc16 = chunk & 15;
      kreg[i] = *(const int4*)((const char*)(Kb + (size_t)krow * ldq) + kc16 * 16);
      int dc = wave + 8 * i;
      vreg[i] = *(const int4*)(Vb + (size_t)lane * ldq + dc * 8);
    }

    for (int t = 0; t < nT; ++t) {
      const int kv0 = t * 64;
      __syncthreads();  // all waves done reading prev tile's (or prev pass's) LDS
      // ---- write staged regs to LDS ----
#pragma unroll
      for (int i = 0; i < 2; i++) {
        int chunk = tid + i * 512, krow = chunk >> 4, kc16 = chunk & 15;
        *(int4*)&Ksm[krow * 256 + ((kc16 ^ (krow & 7)) * 16)] = kreg[i];
        int dc = wave + 8 * i;
        const __hip_bfloat16* e = (const __hip_bfloat16*)&vreg[i];
#pragma unroll
        for (int u = 0; u < 8; u++) Vts[(dc * 8 + u) * VTS + posj] = e[u];
      }
      __syncthreads();
      // ---- issue next tile's loads (overlap with compute below) ----
      if (t + 1 < nT) {
        const int nkv = kv0 + 64;
#pragma unroll
        for (int i = 0; i < 2; i++) {
          int chunk = tid + i * 512, krow = chunk >> 4, kc16 = chunk & 15;
          kreg[i] = *(const int4*)((const char*)(Kb + (size_t)(nkv + krow) * ldq) + kc16 * 16);
          int dc = wave + 8 * i;
          vreg[i] = *(const int4*)(Vb + (size_t)(nkv + lane) * ldq + dc * 8);
        }
      }
      if (kv0 > rmax) continue;  // wave fully masked (barriers already done)

      // ---- S^T = K Q^T: rows kv = nf*16+g*4+r (regs), cols q = l15 ----
      f32x4 sacc[4];
      __builtin_amdgcn_s_setprio(1);
#pragma unroll
      for (int nf = 0; nf < 4; nf++) {
        f32x4 a = {0.f, 0.f, 0.f, 0.f};
        const int n = nf * 16 + l15;  // kv row index for the A-frag read
#pragma unroll
        for (int c = 0; c < 4; c++) {
          int cc = c * 4 + g;
          bf16x8 kf = *(const bf16x8*)&Ksm[n * 256 + ((cc ^ (n & 7)) * 16)];
          a = __builtin_amdgcn_mfma_f32_16x16x32_bf16(kf, aq[c], a, 0, 0, 0);
        }
        sacc[nf] = a;
      }
      __builtin_amdgcn_s_setprio(0);

      // ---- causal mask (unscaled scores) ----
      if (kv0 + 63 > rmin) {
#pragma unroll
        for (int nf = 0; nf < 4; nf++)
#pragma unroll
          for (int r = 0; r < 4; r++)
            if (kv0 + nf * 16 + g * 4 + r > qr) sacc[nf][r] = -3e38f;
      }

      // ---- lane-local softmax (scale folded into exp2) ----
      const float t2e = 0.12751744f;  // (1/sqrt(128)) * log2(e)
      float mx = sacc[0][0];
#pragma unroll
      for (int nf = 0; nf < 4; nf++)
#pragma unroll
        for (int r = 0; r < 4; r++) mx = fmaxf(mx, sacc[nf][r]);
      mx = fmaxf(mx, __shfl_xor(mx, 16, 64));
      mx = fmaxf(mx, __shfl_xor(mx, 32, 64));
      float mnew = fmaxf(m_r, mx);
      float corr = __builtin_amdgcn_exp2f((m_r - mnew) * t2e);
      m_r = mnew;
      float sum = 0.f;
#pragma unroll
      for (int nf = 0; nf < 4; nf++)
#pragma unroll
        for (int r = 0; r < 4; r++) {
          float pv = __builtin_amdgcn_exp2f((sacc[nf][r] - m_r) * t2e);
          sacc[nf][r] = pv;
          sum += pv;
        }
      sum += __shfl_xor(sum, 16, 64);
      sum += __shfl_xor(sum, 32, 64);
      l_r = l_r * corr + sum;
#pragma unroll
      for (int of = 0; of < 8; of++)
#pragma unroll
        for (int r = 0; r < 4; r++) oacc[of][r] *= corr;

      // ---- pack P -> B-frag (pure in-lane; kv order matches Vts permutation)
      bf16x8 pa0, pa1;
#pragma unroll
      for (int r = 0; r < 4; r++) {
        pa0[r]     = (__bf16)sacc[0][r];
        pa0[r + 4] = (__bf16)sacc[1][r];
        pa1[r]     = (__bf16)sacc[2][r];
        pa1[r + 4] = (__bf16)sacc[3][r];
      }

      // ---- O^T += V^T P ----
      __builtin_amdgcn_s_setprio(1);
#pragma unroll
      for (int of = 0; of < 8; of++) {
        const int vrow = of * 16 + l15;
        bf16x8 v0 = *(const bf16x8*)&Vts[vrow * VTS + g * 8];
        bf16x8 v1 = *(const bf16x8*)&Vts[vrow * VTS + 32 + g * 8];
        oacc[of] = __builtin_amdgcn_mfma_f32_16x16x32_bf16(v0, pa0, oacc[of], 0, 0, 0);
        oacc[of] = __builtin_amdgcn_mfma_f32_16x16x32_bf16(v1, pa1, oacc[of], 0, 0, 0);
      }
      __builtin_amdgcn_s_setprio(0);
    }

    // ---- normalize + store y: lane owns q-row l15, d = of*16+g*4+(0..3) ----
    const float inv = 1.0f / l_r;
    __hip_bfloat16* yp = y + ((size_t)b * S + qr) * 2048 + h * 128;
#pragma unroll
    for (int of = 0; of < 8; of++) {
      __hip_bfloat16 o4[4];
#pragma unroll
      for (int r = 0; r < 4; r++) o4[r] = __float2bfloat16(oacc[of][r] * inv);
      *(uint2*)&yp[of * 16 + g * 4] = *(uint2*)o4;
    }
  }
}

// ---------------- launch ----------------
extern "C" void kernel_launch(void* const* d_in, const int* in_sizes, int n_in,
                              void* d_out, int out_size, void* d_ws, size_t ws_size,
                              hipStream_t stream) {
  const float* x = (const float*)d_in[0];
  const float* qkv_w = (const float*)d_in[1];
  const float* qkv_b = (const float*)d_in[2];
  const float* out_w = (const float*)d_in[3];
  const float* out_b = (const float*)d_in[4];
  float* out = (float*)d_out;

  const int B = 4, S = 2048, D = 2048;
  const int M = B * S;  // 8192

  char* ws = (char*)d_ws;
  __hip_bfloat16* xb   = (__hip_bfloat16*)(ws + 0);
  __hip_bfloat16* wqb  = (__hip_bfloat16*)(ws + 33554432);
  __hip_bfloat16* wob  = (__hip_bfloat16*)(ws + 58720256);
  __hip_bfloat16* qkvb = (__hip_bfloat16*)(ws + 67108864);
  __hip_bfloat16* yb   = (__hip_bfloat16*)(ws + 167772160);
  float* cosT          = (float*)(ws + 201326592);
  float* sinT          = (float*)(ws + 201850880);

  cast_f32_bf16<<<M * D / 4 / 256, 256, 0, stream>>>(x, xb, M * D / 4);
  cast_f32_bf16<<<3 * D * D / 4 / 256, 256, 0, stream>>>(qkv_w, wqb, 3 * D * D / 4);
  cast_f32_bf16<<<D * D / 4 / 256, 256, 0, stream>>>(out_w, wob, D * D / 4);
  rope_tables<<<S * 64 / 256, 256, 0, stream>>>(cosT, sinT, S);

  dim3 g1(3 * D / 128, M / 128);
  gemm_bt<1><<<g1, 256, 0, stream>>>(xb, wqb, qkv_b, (void*)qkvb, M, 3 * D, D);

  rope_apply<<<M, 256, 0, stream>>>(qkvb, cosT, sinT);

  dim3 g2(8, B * 16);
  flash_attn<<<g2, 512, 0, stream>>>(qkvb, yb, S);

  dim3 g3(D / 128, M / 128);
  gemm_bt<0><<<g3, 256, 0, stream>>>(yb, wob, out_b, (void*)out, M, D, D);
}

// Round 7
// 590.733 us; speedup vs baseline: 1.7994x; 1.2270x over previous
//
#include <hip/hip_runtime.h>
#include <hip/hip_bf16.h>
#include <math.h>

typedef __bf16 bf16x8 __attribute__((ext_vector_type(8)));
typedef float f32x4 __attribute__((ext_vector_type(4)));

#define GPTR(x) ((const __attribute__((address_space(1))) void*)(x))
#define LPTR(x) ((__attribute__((address_space(3))) void*)(x))

__device__ __forceinline__ void gload_lds16(const void* g, void* l) {
  __builtin_amdgcn_global_load_lds(GPTR(g), LPTR(l), 16, 0, 0);
}

// ---------------- cast fp32 -> bf16, vectorized ----------------
__global__ __launch_bounds__(256) void cast_f32_bf16(const float* __restrict__ in,
                                                     __hip_bfloat16* __restrict__ out,
                                                     int n4) {
  int i = blockIdx.x * 256 + threadIdx.x;
  if (i >= n4) return;
  float4 v = ((const float4*)in)[i];
  __hip_bfloat16 t[4];
  t[0] = __float2bfloat16(v.x); t[1] = __float2bfloat16(v.y);
  t[2] = __float2bfloat16(v.z); t[3] = __float2bfloat16(v.w);
  ((uint2*)out)[i] = *(uint2*)t;
}

// ---------------- RoPE tables: cos/sin[s][j], j<64 ----------------
__global__ __launch_bounds__(256) void rope_tables(float* __restrict__ cosT,
                                                   float* __restrict__ sinT, int S) {
  int i = blockIdx.x * 256 + threadIdx.x;
  if (i >= S * 64) return;
  int j = i & 63, s = i >> 6;
  float freq = powf(10000.0f, -(float)(2 * j) * (1.0f / 128.0f));
  float a = (float)s * freq;
  cosT[i] = cosf(a);
  sinT[i] = sinf(a);
}

// ---------------- RoPE in-place, vectorized: 4 pairs (8 bf16) per thread ----
__global__ __launch_bounds__(256) void rope_apply(__hip_bfloat16* __restrict__ qkv,
                                                  const float* __restrict__ cosT,
                                                  const float* __restrict__ sinT) {
  int i = blockIdx.x * 256 + threadIdx.x;   // M*256 total
  int jc = i & 15;                          // 4-pair chunk within head
  int h = (i >> 4) & 15;
  int row = i >> 8;                         // b*S + s
  int s = row & 2047;                       // S = 2048
  float4 c4 = *(const float4*)&cosT[s * 64 + jc * 4];
  float4 s4 = *(const float4*)&sinT[s * 64 + jc * 4];
  size_t base = (size_t)row * 6144 + h * 128 + jc * 8;
#pragma unroll
  for (int half = 0; half < 2; half++) {
    __hip_bfloat16* p = qkv + base + half * 2048;   // q then k
    bf16x8 v = *(bf16x8*)p;
    bf16x8 o;
    float cc[4] = {c4.x, c4.y, c4.z, c4.w};
    float ss[4] = {s4.x, s4.y, s4.z, s4.w};
#pragma unroll
    for (int u = 0; u < 4; u++) {
      float x1 = (float)v[2 * u], x2 = (float)v[2 * u + 1];
      o[2 * u]     = (__bf16)(x1 * cc[u] - x2 * ss[u]);
      o[2 * u + 1] = (__bf16)(x1 * ss[u] + x2 * cc[u]);
    }
    *(bf16x8*)p = o;
  }
}

// ---------------- GEMM: C[M][N] = A[M][K] @ B[N][K]^T + bias ----------------
// 256x256 tile, BK=64, 8 waves (each 128x64 out), XOR-swizzled LDS
// (16B-chunk ^= row&7; gload_lds dest stays linear, SOURCE pre-swizzled),
// 4 phases/K-tile with staged prefetch, 1 barrier (+vmcnt drain) per K-tile.
template <int OUT_BF16>
__global__ __launch_bounds__(512, 2) void gemm256(const __hip_bfloat16* __restrict__ A,
                                                  const __hip_bfloat16* __restrict__ Bm,
                                                  const float* __restrict__ bias,
                                                  void* __restrict__ Cv,
                                                  int M, int N, int K) {
  __shared__ __align__(16) char lds[2][65536];  // per buf: A[256][64] | B[256][64] bf16
  const int tid = threadIdx.x, wave = tid >> 6;
  const int lane = tid & 63, l15 = lane & 15, g = lane >> 4;
  const int bm = blockIdx.y * 256, bn = blockIdx.x * 256;
  const int wr = wave >> 2, wc = wave & 3;   // wave out-tile: rows wr*128, cols wc*64
  f32x4 acc[8][4] = {};

  // cooperative stage of one 128-row half of A or B (2 x gload_lds / thread).
  // LDS slot (row, c) receives global chunk (c ^ (row&7))  [swizzle involution]
  auto stage = [&](int t, int bufx, int matB, int half) {
#pragma unroll
    for (int j = 0; j < 2; j++) {
      const int rl = j * 64 + (tid >> 3);        // 0..127 row within half
      const int c = tid & 7;                     // 16B chunk 0..7
      const int row = half * 128 + rl;
      const __hip_bfloat16* src =
          (matB ? Bm + (size_t)(bn + row) * K : A + (size_t)(bm + row) * K)
          + (size_t)t * 64 + ((c ^ (row & 7)) << 3);
      char* dst = &lds[bufx][matB * 32768 + half * 16384 + ((j * 512 + (wave << 6)) << 4)];
      gload_lds16(src, dst);
    }
  };

  const int nK = K >> 6;
  // prologue: stage tile 0 into buf0, drain, barrier
  stage(0, 0, 0, 0); stage(0, 0, 0, 1); stage(0, 0, 1, 0); stage(0, 0, 1, 1);
  __syncthreads();

  int cur = 0;
  for (int t = 0; t < nK; ++t) {
    const int nb = cur ^ 1;
    const bool more = (t + 1 < nK);
#pragma unroll
    for (int ph = 0; ph < 4; ph++) {
      const int mh = ph & 1, kh = ph >> 1;
      if (ph == 0 && more) { stage(t + 1, nb, 0, 0); stage(t + 1, nb, 0, 1); }
      if (ph == 1 && more) stage(t + 1, nb, 1, 0);
      if (ph == 2 && more) stage(t + 1, nb, 1, 1);
      bf16x8 af[4], bfr[4];
#pragma unroll
      for (int i = 0; i < 4; i++) {
        const int row = wr * 128 + (mh * 4 + i) * 16 + l15;
        const int c = (kh * 4 + g) ^ (row & 7);
        af[i] = *(const bf16x8*)&lds[cur][row * 128 + c * 16];
      }
#pragma unroll
      for (int j = 0; j < 4; j++) {
        const int col = wc * 64 + j * 16 + l15;
        const int c = (kh * 4 + g) ^ (col & 7);
        bfr[j] = *(const bf16x8*)&lds[cur][32768 + col * 128 + c * 16];
      }
      __builtin_amdgcn_s_setprio(1);
#pragma unroll
      for (int i = 0; i < 4; i++)
#pragma unroll
        for (int j = 0; j < 4; j++)
          acc[mh * 4 + i][j] = __builtin_amdgcn_mfma_f32_16x16x32_bf16(
              af[i], bfr[j], acc[mh * 4 + i][j], 0, 0, 0);
      __builtin_amdgcn_s_setprio(0);
    }
    __syncthreads();  // drains vmcnt (tile t+1 landed) + all waves done reading cur
    cur = nb;
  }

  // epilogue: C frag layout col=lane&15, row=(lane>>4)*4+reg
  const int r0 = bm + wr * 128 + g * 4;
  const int c0 = bn + wc * 64 + l15;
#pragma unroll
  for (int fi = 0; fi < 8; fi++) {
#pragma unroll
    for (int fj = 0; fj < 4; fj++) {
      const int col = c0 + fj * 16;
      const float bv = bias[col];
#pragma unroll
      for (int r = 0; r < 4; r++) {
        const int row = r0 + fi * 16 + r;
        float v = acc[fi][fj][r] + bv;
        if (OUT_BF16)
          ((__hip_bfloat16*)Cv)[(size_t)row * N + col] = __float2bfloat16(v);
        else
          ((float*)Cv)[(size_t)row * N + col] = v;
      }
    }
  }
}

// ---------------- flash attention (swapped-QK^T, paired uniform blocks) -----
// grid: (8, B*H). Block (pi,bh) processes q-tiles (15-pi) then (pi): every
// block does exactly 34 KV-tiles -> zero tail, sustained occupancy.
// 512 thr / 8 waves; wave owns 16 q rows; KVBLK=64, dh=128.
#define VTS 72
__global__ __launch_bounds__(512, 4) void flash_attn(const __hip_bfloat16* __restrict__ qkv,
                                                     __hip_bfloat16* __restrict__ y,
                                                     int S) {
  __shared__ __align__(16) char Ksm[64 * 256];             // K, XOR-swizzled 16B chunks
  __shared__ __align__(16) __hip_bfloat16 Vts[128 * VTS];  // V^T, kv-permuted columns
  const int tid = threadIdx.x, wave = tid >> 6, lane = tid & 63;
  const int l15 = lane & 15, g = lane >> 4;
  const int b = blockIdx.y >> 4, h = blockIdx.y & 15;
  const int pi = blockIdx.x;  // 0..7
  const size_t ldq = 6144;
  const __hip_bfloat16* Qb = qkv + (size_t)b * S * ldq + (size_t)h * 128;
  const __hip_bfloat16* Kb = Qb + 2048;
  const __hip_bfloat16* Vb = Qb + 4096;

  const int posj = ((lane >> 5) << 5) | ((((lane >> 2) & 3)) << 3) |
                   (((lane >> 4) & 1) << 2) | (lane & 3);

  for (int pass = 0; pass < 2; ++pass) {
    const int qt = pass == 0 ? (15 - pi) : pi;   // long tile first
    const int q0 = qt * 128;
    const int qr = q0 + wave * 16 + l15;   // this lane's q row (global)
    const int rmin = q0 + wave * 16, rmax = rmin + 15;

    bf16x8 aq[4];
    {
      const __hip_bfloat16* qp = Qb + (size_t)qr * ldq + g * 8;
#pragma unroll
      for (int c = 0; c < 4; c++) aq[c] = *(const bf16x8*)(qp + c * 32);
    }

    float m_r = -1e30f, l_r = 0.f;
    f32x4 oacc[8] = {};   // O^T: row d = of*16+g*4+r, col q = l15
    const int nT = q0 / 64 + 2;

    int4 kreg[2], vreg[2];
#pragma unroll
    for (int i = 0; i < 2; i++) {   // prologue: prefetch tile 0
      int chunk = tid + i * 512, krow = chunk >> 4, kc16 = chunk & 15;
      kreg[i] = *(const int4*)((const char*)(Kb + (size_t)krow * ldq) + kc16 * 16);
      int dc = wave + 8 * i;
      vreg[i] = *(const int4*)(Vb + (size_t)lane * ldq + dc * 8);
    }

    for (int t = 0; t < nT; ++t) {
      const int kv0 = t * 64;
      __syncthreads();  // all waves done reading prev tile's (or prev pass's) LDS
#pragma unroll
      for (int i = 0; i < 2; i++) {
        int chunk = tid + i * 512, krow = chunk >> 4, kc16 = chunk & 15;
        *(int4*)&Ksm[krow * 256 + ((kc16 ^ (krow & 7)) * 16)] = kreg[i];
        int dc = wave + 8 * i;
        const __hip_bfloat16* e = (const __hip_bfloat16*)&vreg[i];
#pragma unroll
        for (int u = 0; u < 8; u++) Vts[(dc * 8 + u) * VTS + posj] = e[u];
      }
      __syncthreads();
      if (t + 1 < nT) {
        const int nkv = kv0 + 64;
#pragma unroll
        for (int i = 0; i < 2; i++) {
          int chunk = tid + i * 512, krow = chunk >> 4, kc16 = chunk & 15;
          kreg[i] = *(const int4*)((const char*)(Kb + (size_t)(nkv + krow) * ldq) + kc16 * 16);
          int dc = wave + 8 * i;
          vreg[i] = *(const int4*)(Vb + (size_t)(nkv + lane) * ldq + dc * 8);
        }
      }
      if (kv0 > rmax) continue;  // wave fully masked (barriers already done)

      // ---- S^T = K Q^T ----
      f32x4 sacc[4];
      __builtin_amdgcn_s_setprio(1);
#pragma unroll
      for (int nf = 0; nf < 4; nf++) {
        f32x4 a = {0.f, 0.f, 0.f, 0.f};
        const int n = nf * 16 + l15;
#pragma unroll
        for (int c = 0; c < 4; c++) {
          int cc = c * 4 + g;
          bf16x8 kf = *(const bf16x8*)&Ksm[n * 256 + ((cc ^ (n & 7)) * 16)];
          a = __builtin_amdgcn_mfma_f32_16x16x32_bf16(kf, aq[c], a, 0, 0, 0);
        }
        sacc[nf] = a;
      }
      __builtin_amdgcn_s_setprio(0);

      if (kv0 + 63 > rmin) {
#pragma unroll
        for (int nf = 0; nf < 4; nf++)
#pragma unroll
          for (int r = 0; r < 4; r++)
            if (kv0 + nf * 16 + g * 4 + r > qr) sacc[nf][r] = -3e38f;
      }

      // ---- lane-local softmax ----
      const float t2e = 0.12751744f;  // (1/sqrt(128)) * log2(e)
      float mx = sacc[0][0];
#pragma unroll
      for (int nf = 0; nf < 4; nf++)
#pragma unroll
        for (int r = 0; r < 4; r++) mx = fmaxf(mx, sacc[nf][r]);
      mx = fmaxf(mx, __shfl_xor(mx, 16, 64));
      mx = fmaxf(mx, __shfl_xor(mx, 32, 64));
      float mnew = fmaxf(m_r, mx);
      float corr = __builtin_amdgcn_exp2f((m_r - mnew) * t2e);
      m_r = mnew;
      float sum = 0.f;
#pragma unroll
      for (int nf = 0; nf < 4; nf++)
#pragma unroll
        for (int r = 0; r < 4; r++) {
          float pv = __builtin_amdgcn_exp2f((sacc[nf][r] - m_r) * t2e);
          sacc[nf][r] = pv;
          sum += pv;
        }
      sum += __shfl_xor(sum, 16, 64);
      sum += __shfl_xor(sum, 32, 64);
      l_r = l_r * corr + sum;
#pragma unroll
      for (int of = 0; of < 8; of++)
#pragma unroll
        for (int r = 0; r < 4; r++) oacc[of][r] *= corr;

      bf16x8 pa0, pa1;
#pragma unroll
      for (int r = 0; r < 4; r++) {
        pa0[r]     = (__bf16)sacc[0][r];
        pa0[r + 4] = (__bf16)sacc[1][r];
        pa1[r]     = (__bf16)sacc[2][r];
        pa1[r + 4] = (__bf16)sacc[3][r];
      }

      // ---- O^T += V^T P ----
      __builtin_amdgcn_s_setprio(1);
#pragma unroll
      for (int of = 0; of < 8; of++) {
        const int vrow = of * 16 + l15;
        bf16x8 v0 = *(const bf16x8*)&Vts[vrow * VTS + g * 8];
        bf16x8 v1 = *(const bf16x8*)&Vts[vrow * VTS + 32 + g * 8];
        oacc[of] = __builtin_amdgcn_mfma_f32_16x16x32_bf16(v0, pa0, oacc[of], 0, 0, 0);
        oacc[of] = __builtin_amdgcn_mfma_f32_16x16x32_bf16(v1, pa1, oacc[of], 0, 0, 0);
      }
      __builtin_amdgcn_s_setprio(0);
    }

    const float inv = 1.0f / l_r;
    __hip_bfloat16* yp = y + ((size_t)b * S + qr) * 2048 + h * 128;
#pragma unroll
    for (int of = 0; of < 8; of++) {
      __hip_bfloat16 o4[4];
#pragma unroll
      for (int r = 0; r < 4; r++) o4[r] = __float2bfloat16(oacc[of][r] * inv);
      *(uint2*)&yp[of * 16 + g * 4] = *(uint2*)o4;
    }
  }
}

// ---------------- launch ----------------
extern "C" void kernel_launch(void* const* d_in, const int* in_sizes, int n_in,
                              void* d_out, int out_size, void* d_ws, size_t ws_size,
                              hipStream_t stream) {
  const float* x = (const float*)d_in[0];
  const float* qkv_w = (const float*)d_in[1];
  const float* qkv_b = (const float*)d_in[2];
  const float* out_w = (const float*)d_in[3];
  const float* out_b = (const float*)d_in[4];
  float* out = (float*)d_out;

  const int B = 4, S = 2048, D = 2048;
  const int M = B * S;  // 8192

  char* ws = (char*)d_ws;
  __hip_bfloat16* xb   = (__hip_bfloat16*)(ws + 0);
  __hip_bfloat16* wqb  = (__hip_bfloat16*)(ws + 33554432);
  __hip_bfloat16* wob  = (__hip_bfloat16*)(ws + 58720256);
  __hip_bfloat16* qkvb = (__hip_bfloat16*)(ws + 67108864);
  __hip_bfloat16* yb   = (__hip_bfloat16*)(ws + 167772160);
  float* cosT          = (float*)(ws + 201326592);
  float* sinT          = (float*)(ws + 201850880);

  cast_f32_bf16<<<M * D / 4 / 256, 256, 0, stream>>>(x, xb, M * D / 4);
  cast_f32_bf16<<<3 * D * D / 4 / 256, 256, 0, stream>>>(qkv_w, wqb, 3 * D * D / 4);
  cast_f32_bf16<<<D * D / 4 / 256, 256, 0, stream>>>(out_w, wob, D * D / 4);
  rope_tables<<<S * 64 / 256, 256, 0, stream>>>(cosT, sinT, S);

  dim3 g1(3 * D / 256, M / 256);
  gemm256<1><<<g1, 512, 0, stream>>>(xb, wqb, qkv_b, (void*)qkvb, M, 3 * D, D);

  rope_apply<<<M, 256, 0, stream>>>(qkvb, cosT, sinT);

  dim3 g2(8, B * 16);
  flash_attn<<<g2, 512, 0, stream>>>(qkvb, yb, S);

  dim3 g3(D / 256, M / 256);
  gemm256<0><<<g3, 512, 0, stream>>>(yb, wob, out_b, (void*)out, M, D, D);
}